// Round 1
// baseline (81.588 us; speedup 1.0000x reference)
//
#include <hip/hip_runtime.h>

// out[b,0,f] = x[b,0,f]*W[f,0] + x[b,1,f]*W[f,1] + b[f]
// B=8192, DAYS=2, F=4096, all float32.
// Memory-bound streaming kernel: 256 MiB read (x) + 128 MiB write (out).

#define B_DIM 8192
#define F_DIM 4096
#define F4 (F_DIM / 4)          // 1024 float4 per feature row

__global__ void __launch_bounds__(256) conv1x2_fused(
    const float* __restrict__ x,     // [B][2][F]
    const float* __restrict__ W,     // [F][2] interleaved
    const float* __restrict__ bias,  // [F]
    float* __restrict__ out,         // [B][F]
    int total4)                      // B*F/4
{
    const float4* __restrict__ W4 = reinterpret_cast<const float4*>(W);
    const float4* __restrict__ b4 = reinterpret_cast<const float4*>(bias);
    const float4* __restrict__ x4 = reinterpret_cast<const float4*>(x);
    float4* __restrict__ o4 = reinterpret_cast<float4*>(out);

    int stride = gridDim.x * blockDim.x;
    for (int i = blockIdx.x * blockDim.x + threadIdx.x; i < total4; i += stride) {
        int b  = i >> 10;        // i / F4
        int fv = i & (F4 - 1);   // i % F4

        // x[b,0,f..f+3] and x[b,1,f..f+3]
        float4 a0 = x4[(size_t)b * 2 * F4 + fv];
        float4 a1 = x4[(size_t)b * 2 * F4 + F4 + fv];

        // W for features f0..f3: interleaved (w0,w1) pairs -> two float4
        float4 w01 = W4[2 * fv];      // (W[f0,0], W[f0,1], W[f1,0], W[f1,1])
        float4 w23 = W4[2 * fv + 1];  // (W[f2,0], W[f2,1], W[f3,0], W[f3,1])
        float4 bb  = b4[fv];

        float4 o;
        o.x = fmaf(a0.x, w01.x, fmaf(a1.x, w01.y, bb.x));
        o.y = fmaf(a0.y, w01.z, fmaf(a1.y, w01.w, bb.y));
        o.z = fmaf(a0.z, w23.x, fmaf(a1.z, w23.y, bb.z));
        o.w = fmaf(a0.w, w23.z, fmaf(a1.w, w23.w, bb.w));
        o4[i] = o;
    }
}

extern "C" void kernel_launch(void* const* d_in, const int* in_sizes, int n_in,
                              void* d_out, int out_size, void* d_ws, size_t ws_size,
                              hipStream_t stream) {
    const float* x    = (const float*)d_in[0];
    const float* W    = (const float*)d_in[1];
    const float* bias = (const float*)d_in[2];
    float* out        = (float*)d_out;

    int total4 = (B_DIM * F_DIM) / 4;  // 8,388,608
    int block = 256;
    int grid = 2048;                   // 16 iters/thread grid-stride
    conv1x2_fused<<<grid, block, 0, stream>>>(x, W, bias, out, total4);
}

// Round 3
// 75.571 us; speedup vs baseline: 1.0796x; 1.0796x over previous
//
#include <hip/hip_runtime.h>

// out[b,0,f] = x[b,0,f]*W[f,0] + x[b,1,f]*W[f,1] + b[f]
// B=8192, DAYS=2, F=4096, all float32.
// Memory-bound: 256 MiB stream-read (x) + 128 MiB stream-write (out).
// Streams have zero reuse -> nontemporal loads/stores (nt flag) to avoid
// LLC churn (working set 402 MB > 256 MB L3). W/bias stay cached.

#define B_DIM 8192
#define F_DIM 4096
#define F4 (F_DIM / 4)            // 1024 float4 per feature row
#define TOTAL4 (B_DIM * F4)       // 8,388,608 float4 outputs
#define BLOCK 256
#define GRID 2048
#define STRIDE (GRID * BLOCK)     // 524,288
#define ITERS (TOTAL4 / STRIDE)   // 16 exactly, no remainder

// Native clang vector type — required by __builtin_nontemporal_*.
typedef float v4f __attribute__((ext_vector_type(4)));

__global__ void __launch_bounds__(BLOCK) conv1x2_fused(
    const float* __restrict__ x,     // [B][2][F]
    const float* __restrict__ W,     // [F][2] interleaved
    const float* __restrict__ bias,  // [F]
    float* __restrict__ out)         // [B][F]
{
    const v4f* __restrict__ W4 = reinterpret_cast<const v4f*>(W);
    const v4f* __restrict__ b4 = reinterpret_cast<const v4f*>(bias);
    const v4f* __restrict__ x4 = reinterpret_cast<const v4f*>(x);
    v4f* __restrict__ o4 = reinterpret_cast<v4f*>(out);

    int base = blockIdx.x * BLOCK + threadIdx.x;

#pragma unroll 4
    for (int k = 0; k < ITERS; ++k) {
        int i  = base + k * STRIDE;
        int b  = i >> 10;           // i / F4
        int fv = i & (F4 - 1);      // i % F4

        // Streaming reads of x (no reuse) — nontemporal.
        const v4f* p0 = &x4[(size_t)b * 2 * F4 + fv];
        const v4f* p1 = p0 + F4;
        v4f a0 = __builtin_nontemporal_load(p0);
        v4f a1 = __builtin_nontemporal_load(p1);

        // W/bias: tiny, reused by every block — normal cached loads.
        v4f w01 = W4[2 * fv];      // (W[f0,0], W[f0,1], W[f1,0], W[f1,1])
        v4f w23 = W4[2 * fv + 1];  // (W[f2,0], W[f2,1], W[f3,0], W[f3,1])
        v4f bb  = b4[fv];

        v4f o;
        o.x = fmaf(a0.x, w01.x, fmaf(a1.x, w01.y, bb.x));
        o.y = fmaf(a0.y, w01.z, fmaf(a1.y, w01.w, bb.y));
        o.z = fmaf(a0.z, w23.x, fmaf(a1.z, w23.y, bb.z));
        o.w = fmaf(a0.w, w23.z, fmaf(a1.w, w23.w, bb.w));

        // Streaming write (no reuse) — nontemporal.
        __builtin_nontemporal_store(o, &o4[i]);
    }
}

extern "C" void kernel_launch(void* const* d_in, const int* in_sizes, int n_in,
                              void* d_out, int out_size, void* d_ws, size_t ws_size,
                              hipStream_t stream) {
    const float* x    = (const float*)d_in[0];
    const float* W    = (const float*)d_in[1];
    const float* bias = (const float*)d_in[2];
    float* out        = (float*)d_out;

    conv1x2_fused<<<GRID, BLOCK, 0, stream>>>(x, W, bias, out);
}

// Round 4
// 69.685 us; speedup vs baseline: 1.1708x; 1.0845x over previous
//
#include <hip/hip_runtime.h>

// out[b,0,f] = x[b,0,f]*W[f,0] + x[b,1,f]*W[f,1] + b[f]
// B=8192, DAYS=2, F=4096, all float32.
// Memory-bound: 256 MiB stream-read (x) + 128 MiB stream-write (out).
// nt loads/stores bypass LLC allocation for the zero-reuse streams.
// STRIDE % F4 == 0 -> each thread's feature slot fv is loop-invariant:
// W/bias hoisted out of the loop, x/out advance by constant strides.

#define B_DIM 8192
#define F_DIM 4096
#define F4 (F_DIM / 4)            // 1024 float4 per feature row
#define TOTAL4 (B_DIM * F4)       // 8,388,608 float4 outputs
#define BLOCK 256
#define GRID 2048
#define STRIDE (GRID * BLOCK)     // 524,288 (multiple of F4)
#define ITERS (TOTAL4 / STRIDE)   // 16 exactly, no remainder
#define B_STEP (STRIDE / F4)      // 512 batches per iteration step

// Native clang vector type — required by __builtin_nontemporal_*.
typedef float v4f __attribute__((ext_vector_type(4)));

__global__ void __launch_bounds__(BLOCK) conv1x2_fused(
    const float* __restrict__ x,     // [B][2][F]
    const float* __restrict__ W,     // [F][2] interleaved
    const float* __restrict__ bias,  // [F]
    float* __restrict__ out)         // [B][F]
{
    const v4f* __restrict__ W4 = reinterpret_cast<const v4f*>(W);
    const v4f* __restrict__ b4 = reinterpret_cast<const v4f*>(bias);
    const v4f* __restrict__ x4 = reinterpret_cast<const v4f*>(x);
    v4f* __restrict__ o4 = reinterpret_cast<v4f*>(out);

    const int i0 = blockIdx.x * BLOCK + threadIdx.x;
    const int b0 = i0 >> 10;          // starting batch
    const int fv = i0 & (F4 - 1);     // loop-invariant feature slot

    // Hoisted weights/bias (L1/L2-resident, loaded once per thread).
    const v4f w01 = W4[2 * fv];       // (W[f0,0], W[f0,1], W[f1,0], W[f1,1])
    const v4f w23 = W4[2 * fv + 1];   // (W[f2,0], W[f2,1], W[f3,0], W[f3,1])
    const v4f bb  = b4[fv];

    const v4f* px0 = x4 + (size_t)b0 * (2 * F4) + fv;  // day-0
    v4f*       po  = o4 + i0;

#pragma unroll 8
    for (int k = 0; k < ITERS; ++k) {
        v4f a0 = __builtin_nontemporal_load(px0);
        v4f a1 = __builtin_nontemporal_load(px0 + F4);   // day-1

        v4f o;
        o.x = fmaf(a0.x, w01.x, fmaf(a1.x, w01.y, bb.x));
        o.y = fmaf(a0.y, w01.z, fmaf(a1.y, w01.w, bb.y));
        o.z = fmaf(a0.z, w23.x, fmaf(a1.z, w23.y, bb.z));
        o.w = fmaf(a0.w, w23.z, fmaf(a1.w, w23.w, bb.w));
        __builtin_nontemporal_store(o, po);

        px0 += (size_t)B_STEP * (2 * F4);  // +512 batches
        po  += STRIDE;
    }
}

extern "C" void kernel_launch(void* const* d_in, const int* in_sizes, int n_in,
                              void* d_out, int out_size, void* d_ws, size_t ws_size,
                              hipStream_t stream) {
    const float* x    = (const float*)d_in[0];
    const float* W    = (const float*)d_in[1];
    const float* bias = (const float*)d_in[2];
    float* out        = (float*)d_out;

    conv1x2_fused<<<GRID, BLOCK, 0, stream>>>(x, W, bias, out);
}

// Round 5
// 68.654 us; speedup vs baseline: 1.1884x; 1.0150x over previous
//
#include <hip/hip_runtime.h>

// out[b,0,f] = x[b,0,f]*W[f,0] + x[b,1,f]*W[f,1] + b[f]
// B=8192, DAYS=2, F=4096, all float32.
// Memory-bound: 256 MiB stream-read (x) + 128 MiB stream-write (out).
// nt loads for x (zero reuse, avoid LLC churn); PLAIN stores for out —
// full-line stores don't read-allocate, and the cached TCC write path
// (which fillBuffer drives at 7 TB/s) may drain better than nt-bypass.
// STRIDE % F4 == 0 -> fv loop-invariant: W/bias hoisted, pointer-bump loop.

#define B_DIM 8192
#define F_DIM 4096
#define F4 (F_DIM / 4)            // 1024 float4 per feature row
#define TOTAL4 (B_DIM * F4)       // 8,388,608 float4 outputs
#define BLOCK 256
#define GRID 2048
#define STRIDE (GRID * BLOCK)     // 524,288 (multiple of F4)
#define ITERS (TOTAL4 / STRIDE)   // 16 exactly, no remainder
#define B_STEP (STRIDE / F4)      // 512 batches per iteration step

// Native clang vector type — required by __builtin_nontemporal_*.
typedef float v4f __attribute__((ext_vector_type(4)));

__global__ void __launch_bounds__(BLOCK) conv1x2_fused(
    const float* __restrict__ x,     // [B][2][F]
    const float* __restrict__ W,     // [F][2] interleaved
    const float* __restrict__ bias,  // [F]
    float* __restrict__ out)         // [B][F]
{
    const v4f* __restrict__ W4 = reinterpret_cast<const v4f*>(W);
    const v4f* __restrict__ b4 = reinterpret_cast<const v4f*>(bias);
    const v4f* __restrict__ x4 = reinterpret_cast<const v4f*>(x);
    v4f* __restrict__ o4 = reinterpret_cast<v4f*>(out);

    const int i0 = blockIdx.x * BLOCK + threadIdx.x;
    const int b0 = i0 >> 10;          // starting batch
    const int fv = i0 & (F4 - 1);     // loop-invariant feature slot

    // Hoisted weights/bias (L1/L2-resident, loaded once per thread).
    const v4f w01 = W4[2 * fv];       // (W[f0,0], W[f0,1], W[f1,0], W[f1,1])
    const v4f w23 = W4[2 * fv + 1];   // (W[f2,0], W[f2,1], W[f3,0], W[f3,1])
    const v4f bb  = b4[fv];

    const v4f* px0 = x4 + (size_t)b0 * (2 * F4) + fv;  // day-0
    v4f*       po  = o4 + i0;

#pragma unroll 8
    for (int k = 0; k < ITERS; ++k) {
        v4f a0 = __builtin_nontemporal_load(px0);
        v4f a1 = __builtin_nontemporal_load(px0 + F4);   // day-1

        v4f o;
        o.x = fmaf(a0.x, w01.x, fmaf(a1.x, w01.y, bb.x));
        o.y = fmaf(a0.y, w01.z, fmaf(a1.y, w01.w, bb.y));
        o.z = fmaf(a0.z, w23.x, fmaf(a1.z, w23.y, bb.z));
        o.w = fmaf(a0.w, w23.z, fmaf(a1.w, w23.w, bb.w));

        *po = o;   // plain cached store (full line, no read-allocate)

        px0 += (size_t)B_STEP * (2 * F4);  // +512 batches
        po  += STRIDE;
    }
}

extern "C" void kernel_launch(void* const* d_in, const int* in_sizes, int n_in,
                              void* d_out, int out_size, void* d_ws, size_t ws_size,
                              hipStream_t stream) {
    const float* x    = (const float*)d_in[0];
    const float* W    = (const float*)d_in[1];
    const float* bias = (const float*)d_in[2];
    float* out        = (float*)d_out;

    conv1x2_fused<<<GRID, BLOCK, 0, stream>>>(x, W, bias, out);
}